// Round 9
// baseline (86.285 us; speedup 1.0000x reference)
//
#include <hip/hip_runtime.h>

#define NPIX (512*512)
#define KCL 16
#define IMG_STRIDE 1088   // per-image floats: [0..15]=cnt, [32..543]=sums[16][32], [544..1055]=sq[16][32]
#define LAB_OFF 8704      // float offset of packed-u8 label region (= 8*IMG_STRIDE)
#define ZERO_BYTES (LAB_OFF * 4)

typedef __attribute__((ext_vector_type(8))) short bf16x8;
typedef __attribute__((ext_vector_type(4))) float f32x4;
typedef __attribute__((ext_vector_type(4))) int i32x4;

// fp32 -> bf16 round-to-nearest-even
static __device__ __forceinline__ unsigned int bf16rne(float x) {
  unsigned int u = __builtin_bit_cast(unsigned int, x);
  u += 0x7FFFu + ((u >> 16) & 1u);
  return u >> 16;
}
static __device__ __forceinline__ int pk2(float a, float b) {
  return (int)(bf16rne(a) | (bf16rne(b) << 16));
}

#define RS_LEVEL(ARR, HALF, MASK) { \
    const bool hi = (lane & (MASK)) != 0; \
    _Pragma("unroll") \
    for (int j = 0; j < (HALF); ++j) { \
      float send = hi ? ARR[j] : ARR[j + (HALF)]; \
      float recv = __shfl_xor(send, (MASK), 64); \
      ARR[j] = (hi ? ARR[j + (HALF)] : ARR[j]) + recv; \
    } }

// ---------------- prep: pack labels to u8 + per-image cnt ----------------
// 128 blocks = 8 img x 16 seg; 512 threads; 32 labels/thread. (R5-proven)
__global__ void __launch_bounds__(512)
cl_prep(const int* __restrict__ labs, float* __restrict__ ws)
{
  const int b    = blockIdx.x >> 4;
  const int seg  = blockIdx.x & 15;
  const int tid  = threadIdx.x;
  const int lane = tid & 63;
  const int4* lb4 = reinterpret_cast<const int4*>(labs + b * NPIX + seg * 16384);
  unsigned int* lab8 = reinterpret_cast<unsigned int*>(ws + LAB_OFF) +
                       (b * NPIX + seg * 16384) / 4;

  float c[KCL];
  #pragma unroll
  for (int k = 0; k < KCL; ++k) c[k] = 0.f;
  #pragma unroll
  for (int i = 0; i < 8; ++i) {
    const int4 v = lb4[tid + i * 512];
    lab8[tid + i * 512] = (unsigned int)(v.x & 15) | ((unsigned int)(v.y & 15) << 8) |
                          ((unsigned int)(v.z & 15) << 16) | ((unsigned int)(v.w & 15) << 24);
    #pragma unroll
    for (int k = 0; k < KCL; ++k) {
      c[k] += (v.x == k) ? 1.0f : 0.0f;
      c[k] += (v.y == k) ? 1.0f : 0.0f;
      c[k] += (v.z == k) ? 1.0f : 0.0f;
      c[k] += (v.w == k) ? 1.0f : 0.0f;
    }
  }
  RS_LEVEL(c, 8, 1)
  RS_LEVEL(c, 4, 2)
  RS_LEVEL(c, 2, 4)
  RS_LEVEL(c, 1, 8)
  c[0] += __shfl_xor(c[0], 16, 64);
  c[0] += __shfl_xor(c[0], 32, 64);
  if (lane < KCL) {
    const int v4 = (int)(__brev((unsigned)lane) >> 28);
    atomicAdd(&ws[b * IMG_STRIDE + v4], c[0]);
  }
}

// ---------------- accum: linear-stream staged one-hot MFMA ----------------
// grid 512 = 8 img x 4 chgroups(8ch) x 16 pxtiles(16384 px); 512 thr = 8 waves.
// Wave w linearly streams channel cg*8+w (64 KB contiguous; 4 KB/round x 16).
// Compute: one-hot MFMA, A=onehot[k=lane&15][px], B=staged feats
// (cols 0..7 = channels, 8..15 zero). Wave w computes px [w*128,w*128+128).
// LDS rows padded to 1028 floats: read starts spread over all 32 banks
// (4 words/bank = theoretical minimum cycles, zero conflict penalty).
__global__ void __launch_bounds__(512)
cl_accum(const float* __restrict__ feats, float* __restrict__ ws)
{
  const int bid  = blockIdx.x;
  const int pt   = bid & 15;
  const int cg   = (bid >> 4) & 3;
  const int b    = bid >> 6;
  const int tid  = threadIdx.x;
  const int wave = tid >> 6;
  const int lane = tid & 63;
  const int kid  = lane & 15;
  const int sub  = lane >> 4;
  const int px0  = pt * 16384;

  __shared__ float sfeat[2][8][1028];
  __shared__ float red[256];

  if (tid < 256) red[tid] = 0.f;

  const float* fptr = feats + ((long long)(b * 32 + cg * 8 + wave)) * NPIX + px0;
  const unsigned long long* lab64 = reinterpret_cast<const unsigned long long*>(
      reinterpret_cast<const unsigned char*>(ws) + (size_t)ZERO_BYTES + (size_t)b * NPIX + px0);

  f32x4 accs = {0.f, 0.f, 0.f, 0.f};
  f32x4 accq = {0.f, 0.f, 0.f, 0.f};

  float4 pf0, pf1, pf2, pf3;
  // prologue: stage round 0
  pf0 = *reinterpret_cast<const float4*>(fptr + lane * 4);
  pf1 = *reinterpret_cast<const float4*>(fptr + 256 + lane * 4);
  pf2 = *reinterpret_cast<const float4*>(fptr + 512 + lane * 4);
  pf3 = *reinterpret_cast<const float4*>(fptr + 768 + lane * 4);
  *reinterpret_cast<float4*>(&sfeat[0][wave][lane * 4])       = pf0;
  *reinterpret_cast<float4*>(&sfeat[0][wave][256 + lane * 4]) = pf1;
  *reinterpret_cast<float4*>(&sfeat[0][wave][512 + lane * 4]) = pf2;
  *reinterpret_cast<float4*>(&sfeat[0][wave][768 + lane * 4]) = pf3;
  __syncthreads();

  for (int r = 0; r < 16; ++r) {
    const int cur = r & 1, nxt = cur ^ 1;
    if (r < 15) {                       // issue next round's linear loads early
      const float* np = fptr + (r + 1) * 1024;
      pf0 = *reinterpret_cast<const float4*>(np + lane * 4);
      pf1 = *reinterpret_cast<const float4*>(np + 256 + lane * 4);
      pf2 = *reinterpret_cast<const float4*>(np + 512 + lane * 4);
      pf3 = *reinterpret_cast<const float4*>(np + 768 + lane * 4);
    }

    // compute round r: wave's 128 px as 4 groups of 32
    #pragma unroll
    for (int g2 = 0; g2 < 4; ++g2) {
      const unsigned long long lw = lab64[r * 128 + wave * 16 + g2 * 4 + sub];
      bf16x8 af;
      #pragma unroll
      for (int j = 0; j < 8; ++j)
        af[j] = (short)((((int)(lw >> (8 * j)) & 0xFF) == kid) ? 0x3F80 : 0);

      i32x4 wv = {0, 0, 0, 0}, qv = {0, 0, 0, 0};
      if (kid < 8) {
        const float* rp = &sfeat[cur][kid][wave * 128 + g2 * 32 + sub * 8];
        const float4 x0 = *reinterpret_cast<const float4*>(rp);
        const float4 x1 = *reinterpret_cast<const float4*>(rp + 4);
        wv[0] = pk2(x0.x, x0.y); wv[1] = pk2(x0.z, x0.w);
        wv[2] = pk2(x1.x, x1.y); wv[3] = pk2(x1.z, x1.w);
        qv[0] = pk2(x0.x * x0.x, x0.y * x0.y); qv[1] = pk2(x0.z * x0.z, x0.w * x0.w);
        qv[2] = pk2(x1.x * x1.x, x1.y * x1.y); qv[3] = pk2(x1.z * x1.z, x1.w * x1.w);
      }
      accs = __builtin_amdgcn_mfma_f32_16x16x32_bf16(
                 af, __builtin_bit_cast(bf16x8, wv), accs, 0, 0, 0);
      accq = __builtin_amdgcn_mfma_f32_16x16x32_bf16(
                 af, __builtin_bit_cast(bf16x8, qv), accq, 0, 0, 0);
    }
    __syncthreads();                    // all waves done reading buf[cur]

    if (r < 15) {                       // write staged data into buf[nxt]
      *reinterpret_cast<float4*>(&sfeat[nxt][wave][lane * 4])       = pf0;
      *reinterpret_cast<float4*>(&sfeat[nxt][wave][256 + lane * 4]) = pf1;
      *reinterpret_cast<float4*>(&sfeat[nxt][wave][512 + lane * 4]) = pf2;
      *reinterpret_cast<float4*>(&sfeat[nxt][wave][768 + lane * 4]) = pf3;
    }
    __syncthreads();                    // buf[nxt] ready
  }

  // ---- epilogue: D col=kid (channel, <8 valid), row=sub*4+rr (cluster) ----
  if (kid < 8) {
    #pragma unroll
    for (int rr = 0; rr < 4; ++rr) {
      const int k = sub * 4 + rr;
      atomicAdd(&red[k * 8 + kid],       accs[rr]);
      atomicAdd(&red[128 + k * 8 + kid], accq[rr]);
    }
  }
  __syncthreads();
  if (tid < 128) {
    const int k  = tid >> 3;
    const int ch = (tid & 7) + cg * 8;
    atomicAdd(&ws[b * IMG_STRIDE + 32  + k * 32 + ch], red[tid]);
    atomicAdd(&ws[b * IMG_STRIDE + 544 + k * 32 + ch], red[128 + tid]);
  }
}

// ---------------- finalize: 1 block, 512 threads; wave w = image w ----------------
__global__ void __launch_bounds__(512)
cl_finalize(const float* __restrict__ ws, float* __restrict__ out)
{
  __shared__ float smean[8][KCL][33];
  __shared__ float slossb[8];
  const int tid  = threadIdx.x;
  const int w    = tid >> 6;
  const int lane = tid & 63;
  const float* base = ws + w * IMG_STRIDE;

  const int kl = lane >> 2;
  const float ik = 1.0f / base[kl];

  float m2part = 0.f, sqpart = 0.f;
  #pragma unroll
  for (int j = 0; j < 8; ++j) {
    const int idx = lane * 8 + j;
    const int c = idx & 31;
    const float m = base[32 + idx] * ik;
    smean[w][kl][c] = m;
    m2part = fmaf(m, m, m2part);
    sqpart += base[544 + idx];
  }
  float varp = fmaf(sqpart, ik, -m2part);
  #pragma unroll
  for (int mk = 1; mk < 64; mk <<= 1) varp += __shfl_xor(varp, mk, 64);

  __syncthreads();

  const int kk = lane >> 2, q = lane & 3;
  float n2 = 0.f;
  #pragma unroll
  for (int j = 0; j < 8; ++j) {
    const float m = smean[w][kk][q * 8 + j];
    n2 = fmaf(m, m, n2);
  }
  n2 += __shfl_xor(n2, 1, 64);
  n2 += __shfl_xor(n2, 2, 64);
  float regp = (q == 0) ? sqrtf(n2) : 0.f;
  #pragma unroll
  for (int mk = 1; mk < 64; mk <<= 1) regp += __shfl_xor(regp, mk, 64);

  float hing = 0.f;
  for (int p = lane; p < 120; p += 64) {
    int i = 0, rem = p;
    while (rem >= 15 - i) { rem -= 15 - i; ++i; }
    const int jj = i + 1 + rem;
    float d2 = 0.f;
    #pragma unroll
    for (int c = 0; c < 32; ++c) {
      const float d = smean[w][i][c] - smean[w][jj][c];
      d2 = fmaf(d, d, d2);
    }
    const float h = fmaxf(5.0f - sqrtf(d2), 0.f);   // 2*DD = 5.0
    hing = fmaf(h, h, hing);
  }
  #pragma unroll
  for (int mk = 1; mk < 64; mk <<= 1) hing += __shfl_xor(hing, mk, 64);

  if (lane == 0)
    slossb[w] = (varp + hing * (1.0f / 15.0f) + 0.005f * regp) * (1.0f / 16.0f);
  __syncthreads();
  if (tid == 0) {
    float t = 0.f;
    #pragma unroll
    for (int i = 0; i < 8; ++i) t += slossb[i];
    out[0] = t * (1.0f / 9.0f);
  }
}

extern "C" void kernel_launch(void* const* d_in, const int* in_sizes, int n_in,
                              void* d_out, int out_size, void* d_ws, size_t ws_size,
                              hipStream_t stream)
{
  const float* feats = (const float*)d_in[0];
  const int*   labs  = (const int*)d_in[1];
  float* out = (float*)d_out;
  float* ws  = (float*)d_ws;

  (void)hipMemsetAsync(d_ws, 0, ZERO_BYTES, stream);
  hipLaunchKernelGGL(cl_prep,     dim3(128), dim3(512), 0, stream, labs, ws);
  hipLaunchKernelGGL(cl_accum,    dim3(512), dim3(512), 0, stream, feats, ws);
  hipLaunchKernelGGL(cl_finalize, dim3(1),   dim3(512), 0, stream, ws, out);
}

// Round 10
// 83.544 us; speedup vs baseline: 1.0328x; 1.0328x over previous
//
#include <hip/hip_runtime.h>

#define NPIX (512*512)
#define KCL 16
#define IMG_STRIDE 1088   // per-image floats: [0..15]=cnt, [32..543]=sums[16][32], [544..1055]=sq[16][32]
#define ZERO_BYTES (8 * IMG_STRIDE * 4)

typedef __attribute__((ext_vector_type(8))) short bf16x8;
typedef __attribute__((ext_vector_type(4))) float f32x4;
typedef __attribute__((ext_vector_type(4))) int i32x4;

// fp32 -> bf16 round-to-nearest-even
static __device__ __forceinline__ unsigned int bf16rne(float x) {
  unsigned int u = __builtin_bit_cast(unsigned int, x);
  u += 0x7FFFu + ((u >> 16) & 1u);
  return u >> 16;
}
static __device__ __forceinline__ int pk2(float a, float b) {
  return (int)(bf16rne(a) | (bf16rne(b) << 16));
}

#define RS_LEVEL(ARR, HALF, MASK) { \
    const bool hi = (lane & (MASK)) != 0; \
    _Pragma("unroll") \
    for (int j = 0; j < (HALF); ++j) { \
      float send = hi ? ARR[j] : ARR[j + (HALF)]; \
      float recv = __shfl_xor(send, (MASK), 64); \
      ARR[j] = (hi ? ARR[j + (HALF)] : ARR[j]) + recv; \
    } }

// ---------------- accum: one-hot MFMA kernel (R8 + mem-path fixes) ----------------
// 512 blocks = 8 img x 64 pxtiles(4096 px); 512 threads = 8 waves.
// Wave w owns px [w*512, w*512+512) as 16 groups of 32 px.
// Lane (kid=lane&15, sub=lane>>4):
//   B slot j<4 : px = sub*4 + j      (x0 = 16B at channel-offset sub*16)
//   B slot j>=4: px = 16 + sub*4 + (j-4)  (x1 = 16B at 64B + sub*16)
// -> each load instruction covers 16 channels x 64 B CONTIGUOUS (vs 64x16B scatter).
// A uses the same k-slot->px map (bijection, shared by A and B => sum over px intact).
// g-loop order skewed per (wave,tile) to decorrelate channel phase (sum-order free).
__global__ void __launch_bounds__(512)
cl_accum(const float* __restrict__ feats, const int* __restrict__ labs,
         float* __restrict__ ws)
{
  const int bid  = blockIdx.x;
  const int tile = bid & 63;
  const int b    = bid >> 6;
  const int tid  = threadIdx.x;
  const int wave = tid >> 6;
  const int lane = tid & 63;
  const int px0  = tile * 4096;

  __shared__ unsigned int slabw[1024];   // packed u8 labels, 4096 px
  __shared__ float red[1024];            // [0..511]=sums[16][32], [512..1023]=sq
  __shared__ float hpart[8][KCL];

  // ---- stage labels (packed u8) + per-thread histogram of its 8 labels ----
  {
    float c[KCL];
    #pragma unroll
    for (int k = 0; k < KCL; ++k) c[k] = 0.f;
    const int4* lb4 = reinterpret_cast<const int4*>(labs + b * NPIX + px0);
    #pragma unroll
    for (int i = 0; i < 2; ++i) {
      const int4 v = lb4[tid + i * 512];
      slabw[tid + i * 512] = (unsigned int)v.x | ((unsigned int)v.y << 8) |
                             ((unsigned int)v.z << 16) | ((unsigned int)v.w << 24);
      #pragma unroll
      for (int k = 0; k < KCL; ++k) {
        c[k] += (v.x == k) ? 1.0f : 0.0f;
        c[k] += (v.y == k) ? 1.0f : 0.0f;
        c[k] += (v.z == k) ? 1.0f : 0.0f;
        c[k] += (v.w == k) ? 1.0f : 0.0f;
      }
    }
    red[tid] = 0.f;
    red[tid + 512] = 0.f;
    RS_LEVEL(c, 8, 1)
    RS_LEVEL(c, 4, 2)
    RS_LEVEL(c, 2, 4)
    RS_LEVEL(c, 1, 8)
    c[0] += __shfl_xor(c[0], 16, 64);
    c[0] += __shfl_xor(c[0], 32, 64);
    if (lane < KCL) {
      const int v4 = (int)(__brev((unsigned)lane) >> 28);
      hpart[wave][v4] = c[0];
    }
  }
  __syncthreads();
  if (tid < KCL) {
    float t = 0.f;
    #pragma unroll
    for (int w = 0; w < 8; ++w) t += hpart[w][tid];
    atomicAdd(&ws[b * IMG_STRIDE + tid], t);   // cnt
  }

  // ---- main MFMA loop ----
  const int kid = lane & 15;
  const int sub = lane >> 4;             // 0..3
  const float* fA = feats + ((long long)(b * 32 + kid)) * NPIX
                    + px0 + wave * 512 + sub * 4;          // sub*16B contiguous map
  const float* fB = fA + (long long)16 * NPIX;
  const int lwbase = wave * 128;         // u32-word base of this wave's labels

  f32x4 accs0 = {0.f, 0.f, 0.f, 0.f};
  f32x4 accs1 = {0.f, 0.f, 0.f, 0.f};
  f32x4 accq0 = {0.f, 0.f, 0.f, 0.f};
  f32x4 accq1 = {0.f, 0.f, 0.f, 0.f};

  #pragma unroll 4
  for (int g0 = 0; g0 < 16; ++g0) {
    const int g = (g0 + wave * 2 + tile) & 15;   // channel-phase skew (order-free)
    // labels for this lane's 8 slots: px sub*4..+3 and 16+sub*4..+3 of group g
    const unsigned int l0 = slabw[lwbase + g * 8 + sub];
    const unsigned int l1 = slabw[lwbase + g * 8 + 4 + sub];
    bf16x8 af;
    #pragma unroll
    for (int j = 0; j < 4; ++j) {
      af[j]     = (short)((((int)(l0 >> (8 * j)) & 0xFF) == kid) ? 0x3F80 : 0);
      af[4 + j] = (short)((((int)(l1 >> (8 * j)) & 0xFF) == kid) ? 0x3F80 : 0);
    }

    // half 0: channels [0..15]
    {
      const f32x4 x0 = __builtin_nontemporal_load(
          reinterpret_cast<const f32x4*>(fA + g * 32));
      const f32x4 x1 = __builtin_nontemporal_load(
          reinterpret_cast<const f32x4*>(fA + g * 32 + 16));
      i32x4 wv, qv;
      wv[0] = pk2(x0[0], x0[1]); wv[1] = pk2(x0[2], x0[3]);
      wv[2] = pk2(x1[0], x1[1]); wv[3] = pk2(x1[2], x1[3]);
      qv[0] = pk2(x0[0] * x0[0], x0[1] * x0[1]); qv[1] = pk2(x0[2] * x0[2], x0[3] * x0[3]);
      qv[2] = pk2(x1[0] * x1[0], x1[1] * x1[1]); qv[3] = pk2(x1[2] * x1[2], x1[3] * x1[3]);
      accs0 = __builtin_amdgcn_mfma_f32_16x16x32_bf16(
                  af, __builtin_bit_cast(bf16x8, wv), accs0, 0, 0, 0);
      accq0 = __builtin_amdgcn_mfma_f32_16x16x32_bf16(
                  af, __builtin_bit_cast(bf16x8, qv), accq0, 0, 0, 0);
    }
    // half 1: channels [16..31]
    {
      const f32x4 x0 = __builtin_nontemporal_load(
          reinterpret_cast<const f32x4*>(fB + g * 32));
      const f32x4 x1 = __builtin_nontemporal_load(
          reinterpret_cast<const f32x4*>(fB + g * 32 + 16));
      i32x4 wv, qv;
      wv[0] = pk2(x0[0], x0[1]); wv[1] = pk2(x0[2], x0[3]);
      wv[2] = pk2(x1[0], x1[1]); wv[3] = pk2(x1[2], x1[3]);
      qv[0] = pk2(x0[0] * x0[0], x0[1] * x0[1]); qv[1] = pk2(x0[2] * x0[2], x0[3] * x0[3]);
      qv[2] = pk2(x1[0] * x1[0], x1[1] * x1[1]); qv[3] = pk2(x1[2] * x1[2], x1[3] * x1[3]);
      accs1 = __builtin_amdgcn_mfma_f32_16x16x32_bf16(
                  af, __builtin_bit_cast(bf16x8, wv), accs1, 0, 0, 0);
      accq1 = __builtin_amdgcn_mfma_f32_16x16x32_bf16(
                  af, __builtin_bit_cast(bf16x8, qv), accq1, 0, 0, 0);
    }
  }

  // ---- cross-wave LDS reduce, then per-block global atomics ----
  // D layout unchanged from verified R8: col=kid (channel-within-half), row=sub*4+r (k)
  #pragma unroll
  for (int r = 0; r < 4; ++r) {
    const int k = sub * 4 + r;
    atomicAdd(&red[k * 32 + kid],            accs0[r]);
    atomicAdd(&red[k * 32 + 16 + kid],       accs1[r]);
    atomicAdd(&red[512 + k * 32 + kid],      accq0[r]);
    atomicAdd(&red[512 + k * 32 + 16 + kid], accq1[r]);
  }
  __syncthreads();
  atomicAdd(&ws[b * IMG_STRIDE + 32 + tid],  red[tid]);        // sums
  atomicAdd(&ws[b * IMG_STRIDE + 544 + tid], red[512 + tid]);  // sq
}

// ---------------- finalize: 1 block, 512 threads; wave w = image w ----------------
__global__ void __launch_bounds__(512)
cl_finalize(const float* __restrict__ ws, float* __restrict__ out)
{
  __shared__ float smean[8][KCL][33];
  __shared__ float slossb[8];
  const int tid  = threadIdx.x;
  const int w    = tid >> 6;
  const int lane = tid & 63;
  const float* base = ws + w * IMG_STRIDE;

  const int kl = lane >> 2;
  const float ik = 1.0f / base[kl];

  float m2part = 0.f, sqpart = 0.f;
  #pragma unroll
  for (int j = 0; j < 8; ++j) {
    const int idx = lane * 8 + j;
    const int c = idx & 31;
    const float m = base[32 + idx] * ik;
    smean[w][kl][c] = m;
    m2part = fmaf(m, m, m2part);
    sqpart += base[544 + idx];
  }
  float varp = fmaf(sqpart, ik, -m2part);
  #pragma unroll
  for (int mk = 1; mk < 64; mk <<= 1) varp += __shfl_xor(varp, mk, 64);

  __syncthreads();

  const int kk = lane >> 2, q = lane & 3;
  float n2 = 0.f;
  #pragma unroll
  for (int j = 0; j < 8; ++j) {
    const float m = smean[w][kk][q * 8 + j];
    n2 = fmaf(m, m, n2);
  }
  n2 += __shfl_xor(n2, 1, 64);
  n2 += __shfl_xor(n2, 2, 64);
  float regp = (q == 0) ? sqrtf(n2) : 0.f;
  #pragma unroll
  for (int mk = 1; mk < 64; mk <<= 1) regp += __shfl_xor(regp, mk, 64);

  float hing = 0.f;
  for (int p = lane; p < 120; p += 64) {
    int i = 0, rem = p;
    while (rem >= 15 - i) { rem -= 15 - i; ++i; }
    const int jj = i + 1 + rem;
    float d2 = 0.f;
    #pragma unroll
    for (int c = 0; c < 32; ++c) {
      const float d = smean[w][i][c] - smean[w][jj][c];
      d2 = fmaf(d, d, d2);
    }
    const float h = fmaxf(5.0f - sqrtf(d2), 0.f);   // 2*DD = 5.0
    hing = fmaf(h, h, hing);
  }
  #pragma unroll
  for (int mk = 1; mk < 64; mk <<= 1) hing += __shfl_xor(hing, mk, 64);

  if (lane == 0)
    slossb[w] = (varp + hing * (1.0f / 15.0f) + 0.005f * regp) * (1.0f / 16.0f);
  __syncthreads();
  if (tid == 0) {
    float t = 0.f;
    #pragma unroll
    for (int i = 0; i < 8; ++i) t += slossb[i];
    out[0] = t * (1.0f / 9.0f);
  }
}

extern "C" void kernel_launch(void* const* d_in, const int* in_sizes, int n_in,
                              void* d_out, int out_size, void* d_ws, size_t ws_size,
                              hipStream_t stream)
{
  const float* feats = (const float*)d_in[0];
  const int*   labs  = (const int*)d_in[1];
  float* out = (float*)d_out;
  float* ws  = (float*)d_ws;

  (void)hipMemsetAsync(d_ws, 0, ZERO_BYTES, stream);
  hipLaunchKernelGGL(cl_accum,    dim3(512), dim3(512), 0, stream, feats, labs, ws);
  hipLaunchKernelGGL(cl_finalize, dim3(1),   dim3(512), 0, stream, ws, out);
}

// Round 11
// 70.615 us; speedup vs baseline: 1.2219x; 1.1831x over previous
//
#include <hip/hip_runtime.h>

#define NPIX (512*512)
#define KCL 16
#define IMG_STRIDE 1088   // per-image floats: [0..15]=cnt, [32..543]=sums[16][32], [544..1055]=sq[16][32]
#define ZERO_BYTES (8 * IMG_STRIDE * 4)

typedef __attribute__((ext_vector_type(8))) short bf16x8;
typedef __attribute__((ext_vector_type(4))) float f32x4;
typedef __attribute__((ext_vector_type(4))) int i32x4;

// fp32 -> bf16 round-to-nearest-even
static __device__ __forceinline__ unsigned int bf16rne(float x) {
  unsigned int u = __builtin_bit_cast(unsigned int, x);
  u += 0x7FFFu + ((u >> 16) & 1u);
  return u >> 16;
}
static __device__ __forceinline__ int pk2(float a, float b) {
  return (int)(bf16rne(a) | (bf16rne(b) << 16));
}

#define RS_LEVEL(ARR, HALF, MASK) { \
    const bool hi = (lane & (MASK)) != 0; \
    _Pragma("unroll") \
    for (int j = 0; j < (HALF); ++j) { \
      float send = hi ? ARR[j] : ARR[j + (HALF)]; \
      float recv = __shfl_xor(send, (MASK), 64); \
      ARR[j] = (hi ? ARR[j + (HALF)] : ARR[j]) + recv; \
    } }

// ---------------- accum: one-hot MFMA kernel (R8 base, occupancy-tuned) ----------------
// 512 blocks = 8 img x 64 pxtiles(4096 px); 512 threads = 8 waves.
// Wave w owns px [w*512, w*512+512) as 16 groups of 32 px.
// R8 lane map restored: lane(kid=lane&15, sub=lane>>4) loads x0 at sub*32B,
// x1 at sub*32B+16B of channel kid's 128B px-chunk (x1 is an L1 line hit).
// Changes vs R8: unroll 2 (live set ~105 VGPR) + __launch_bounds__(512,4)
// -> 2 blocks/CU (16 waves/CU) for 2x wave-level latency hiding.
__global__ void __launch_bounds__(512, 4)
cl_accum(const float* __restrict__ feats, const int* __restrict__ labs,
         float* __restrict__ ws)
{
  const int bid  = blockIdx.x;
  const int tile = bid & 63;
  const int b    = bid >> 6;
  const int tid  = threadIdx.x;
  const int wave = tid >> 6;
  const int lane = tid & 63;
  const int px0  = tile * 4096;

  __shared__ unsigned int slabw[1024];   // packed u8 labels, 4096 px
  __shared__ float red[1024];            // [0..511]=sums[16][32], [512..1023]=sq
  __shared__ float hpart[8][KCL];

  // ---- stage labels (packed u8) + per-thread histogram of its 8 labels ----
  {
    float c[KCL];
    #pragma unroll
    for (int k = 0; k < KCL; ++k) c[k] = 0.f;
    const int4* lb4 = reinterpret_cast<const int4*>(labs + b * NPIX + px0);
    #pragma unroll
    for (int i = 0; i < 2; ++i) {
      const int4 v = lb4[tid + i * 512];
      slabw[tid + i * 512] = (unsigned int)v.x | ((unsigned int)v.y << 8) |
                             ((unsigned int)v.z << 16) | ((unsigned int)v.w << 24);
      #pragma unroll
      for (int k = 0; k < KCL; ++k) {
        c[k] += (v.x == k) ? 1.0f : 0.0f;
        c[k] += (v.y == k) ? 1.0f : 0.0f;
        c[k] += (v.z == k) ? 1.0f : 0.0f;
        c[k] += (v.w == k) ? 1.0f : 0.0f;
      }
    }
    red[tid] = 0.f;
    red[tid + 512] = 0.f;
    RS_LEVEL(c, 8, 1)
    RS_LEVEL(c, 4, 2)
    RS_LEVEL(c, 2, 4)
    RS_LEVEL(c, 1, 8)
    c[0] += __shfl_xor(c[0], 16, 64);
    c[0] += __shfl_xor(c[0], 32, 64);
    if (lane < KCL) {
      const int v4 = (int)(__brev((unsigned)lane) >> 28);
      hpart[wave][v4] = c[0];
    }
  }
  __syncthreads();
  if (tid < KCL) {
    float t = 0.f;
    #pragma unroll
    for (int w = 0; w < 8; ++w) t += hpart[w][tid];
    atomicAdd(&ws[b * IMG_STRIDE + tid], t);   // cnt
  }

  // ---- main MFMA loop (R8 layout) ----
  const int kid = lane & 15;
  const int sub = lane >> 4;             // 0..3
  const float* fA = feats + ((long long)(b * 32 + kid)) * NPIX
                    + px0 + wave * 512 + sub * 8;
  const float* fB = fA + (long long)16 * NPIX;
  const unsigned long long* slq =
      reinterpret_cast<const unsigned long long*>(slabw) + wave * 64 + sub;

  f32x4 accs0 = {0.f, 0.f, 0.f, 0.f};
  f32x4 accs1 = {0.f, 0.f, 0.f, 0.f};
  f32x4 accq0 = {0.f, 0.f, 0.f, 0.f};
  f32x4 accq1 = {0.f, 0.f, 0.f, 0.f};

  #pragma unroll 2
  for (int g = 0; g < 16; ++g) {
    // issue all 4 load instructions up front (x1s hit the lines x0s fetched)
    const float4 a0 = *reinterpret_cast<const float4*>(fA + g * 32);
    const float4 a1 = *reinterpret_cast<const float4*>(fA + g * 32 + 4);
    const float4 b0 = *reinterpret_cast<const float4*>(fB + g * 32);
    const float4 b1 = *reinterpret_cast<const float4*>(fB + g * 32 + 4);

    const unsigned long long lw = slq[g * 4];   // 8 labels for this lane's px
    bf16x8 af;
    #pragma unroll
    for (int j = 0; j < 8; ++j)
      af[j] = (short)((((int)(lw >> (8 * j)) & 0xFF) == kid) ? 0x3F80 : 0);

    // half 0: channels [0..15]
    {
      i32x4 wv, qv;
      wv[0] = pk2(a0.x, a0.y); wv[1] = pk2(a0.z, a0.w);
      wv[2] = pk2(a1.x, a1.y); wv[3] = pk2(a1.z, a1.w);
      qv[0] = pk2(a0.x * a0.x, a0.y * a0.y); qv[1] = pk2(a0.z * a0.z, a0.w * a0.w);
      qv[2] = pk2(a1.x * a1.x, a1.y * a1.y); qv[3] = pk2(a1.z * a1.z, a1.w * a1.w);
      accs0 = __builtin_amdgcn_mfma_f32_16x16x32_bf16(
                  af, __builtin_bit_cast(bf16x8, wv), accs0, 0, 0, 0);
      accq0 = __builtin_amdgcn_mfma_f32_16x16x32_bf16(
                  af, __builtin_bit_cast(bf16x8, qv), accq0, 0, 0, 0);
    }
    // half 1: channels [16..31]
    {
      i32x4 wv, qv;
      wv[0] = pk2(b0.x, b0.y); wv[1] = pk2(b0.z, b0.w);
      wv[2] = pk2(b1.x, b1.y); wv[3] = pk2(b1.z, b1.w);
      qv[0] = pk2(b0.x * b0.x, b0.y * b0.y); qv[1] = pk2(b0.z * b0.z, b0.w * b0.w);
      qv[2] = pk2(b1.x * b1.x, b1.y * b1.y); qv[3] = pk2(b1.z * b1.z, b1.w * b1.w);
      accs1 = __builtin_amdgcn_mfma_f32_16x16x32_bf16(
                  af, __builtin_bit_cast(bf16x8, wv), accs1, 0, 0, 0);
      accq1 = __builtin_amdgcn_mfma_f32_16x16x32_bf16(
                  af, __builtin_bit_cast(bf16x8, qv), accq1, 0, 0, 0);
    }
  }

  // ---- cross-wave LDS reduce, then per-block global atomics ----
  // D layout (R8-verified): col=kid (channel-within-half), row=sub*4+r (k)
  #pragma unroll
  for (int r = 0; r < 4; ++r) {
    const int k = sub * 4 + r;
    atomicAdd(&red[k * 32 + kid],            accs0[r]);
    atomicAdd(&red[k * 32 + 16 + kid],       accs1[r]);
    atomicAdd(&red[512 + k * 32 + kid],      accq0[r]);
    atomicAdd(&red[512 + k * 32 + 16 + kid], accq1[r]);
  }
  __syncthreads();
  atomicAdd(&ws[b * IMG_STRIDE + 32 + tid],  red[tid]);        // sums
  atomicAdd(&ws[b * IMG_STRIDE + 544 + tid], red[512 + tid]);  // sq
}

// ---------------- finalize: 1 block, 512 threads; wave w = image w ----------------
__global__ void __launch_bounds__(512)
cl_finalize(const float* __restrict__ ws, float* __restrict__ out)
{
  __shared__ float smean[8][KCL][33];
  __shared__ float slossb[8];
  const int tid  = threadIdx.x;
  const int w    = tid >> 6;
  const int lane = tid & 63;
  const float* base = ws + w * IMG_STRIDE;

  const int kl = lane >> 2;
  const float ik = 1.0f / base[kl];

  float m2part = 0.f, sqpart = 0.f;
  #pragma unroll
  for (int j = 0; j < 8; ++j) {
    const int idx = lane * 8 + j;
    const int c = idx & 31;
    const float m = base[32 + idx] * ik;
    smean[w][kl][c] = m;
    m2part = fmaf(m, m, m2part);
    sqpart += base[544 + idx];
  }
  float varp = fmaf(sqpart, ik, -m2part);
  #pragma unroll
  for (int mk = 1; mk < 64; mk <<= 1) varp += __shfl_xor(varp, mk, 64);

  __syncthreads();

  const int kk = lane >> 2, q = lane & 3;
  float n2 = 0.f;
  #pragma unroll
  for (int j = 0; j < 8; ++j) {
    const float m = smean[w][kk][q * 8 + j];
    n2 = fmaf(m, m, n2);
  }
  n2 += __shfl_xor(n2, 1, 64);
  n2 += __shfl_xor(n2, 2, 64);
  float regp = (q == 0) ? sqrtf(n2) : 0.f;
  #pragma unroll
  for (int mk = 1; mk < 64; mk <<= 1) regp += __shfl_xor(regp, mk, 64);

  float hing = 0.f;
  for (int p = lane; p < 120; p += 64) {
    int i = 0, rem = p;
    while (rem >= 15 - i) { rem -= 15 - i; ++i; }
    const int jj = i + 1 + rem;
    float d2 = 0.f;
    #pragma unroll
    for (int c = 0; c < 32; ++c) {
      const float d = smean[w][i][c] - smean[w][jj][c];
      d2 = fmaf(d, d, d2);
    }
    const float h = fmaxf(5.0f - sqrtf(d2), 0.f);   // 2*DD = 5.0
    hing = fmaf(h, h, hing);
  }
  #pragma unroll
  for (int mk = 1; mk < 64; mk <<= 1) hing += __shfl_xor(hing, mk, 64);

  if (lane == 0)
    slossb[w] = (varp + hing * (1.0f / 15.0f) + 0.005f * regp) * (1.0f / 16.0f);
  __syncthreads();
  if (tid == 0) {
    float t = 0.f;
    #pragma unroll
    for (int i = 0; i < 8; ++i) t += slossb[i];
    out[0] = t * (1.0f / 9.0f);
  }
}

extern "C" void kernel_launch(void* const* d_in, const int* in_sizes, int n_in,
                              void* d_out, int out_size, void* d_ws, size_t ws_size,
                              hipStream_t stream)
{
  const float* feats = (const float*)d_in[0];
  const int*   labs  = (const int*)d_in[1];
  float* out = (float*)d_out;
  float* ws  = (float*)d_ws;

  (void)hipMemsetAsync(d_ws, 0, ZERO_BYTES, stream);
  hipLaunchKernelGGL(cl_accum,    dim3(512), dim3(512), 0, stream, feats, labs, ws);
  hipLaunchKernelGGL(cl_finalize, dim3(1),   dim3(512), 0, stream, ws, out);
}